// Round 2
// baseline (1388.408 us; speedup 1.0000x reference)
//
#include <hip/hip_runtime.h>

// AttentionLayer: B=8 T=256 M=64 D=512 H=8 DK=64.
// R2: qkv_attn drops x LDS tile (x_bf16 parked in the attn ws region, read as
// 16B global frags), Ps aliased onto qs, O held in packed regs -> LDS 55.3 KB,
// 2 WGs/CU. out_proj rebuilt m97-style (global_load_lds width-16, b128 frags).
// Workspace: 136,314,880 bytes (same as R1).

typedef unsigned short u16;
typedef short s8v __attribute__((ext_vector_type(8)));
typedef unsigned short us4 __attribute__((ext_vector_type(4)));
typedef unsigned short us8 __attribute__((ext_vector_type(8)));
typedef __bf16 bf8v __attribute__((ext_vector_type(8)));
typedef float f4v __attribute__((ext_vector_type(4)));
typedef float fl4 __attribute__((ext_vector_type(4)));

#define LQ 72  // q/k/v/P row stride (u16): 144 B, 16B-aligned, 36 dw == 4 mod 32

static __device__ __forceinline__ u16 f2bf(float f) {
  union { float f; unsigned u; } v;
  v.f = f;
  unsigned r = v.u + 0x7fffu + ((v.u >> 16) & 1u);  // RNE
  return (u16)(r >> 16);
}

static __device__ __forceinline__ s8v ld16(const u16* p) {  // 16B load (LDS or global)
  return *(const s8v*)p;
}

static __device__ __forceinline__ f4v mfma16(s8v a, s8v b, f4v c) {
  return __builtin_amdgcn_mfma_f32_16x16x32_bf16(
      __builtin_bit_cast(bf8v, a), __builtin_bit_cast(bf8v, b), c, 0, 0, 0);
}

// async global->LDS, 16B per lane; lds dest = wave-uniform base + lane*16
#define ASYNC16(g, l)                                                  \
  __builtin_amdgcn_global_load_lds(                                    \
      (const __attribute__((address_space(1))) void*)(g),              \
      (__attribute__((address_space(3))) void*)(l), 16, 0, 0)

// ---------------------------------------------------------------- weights
__global__ __launch_bounds__(256) void pack_weights_kernel(
    const float* __restrict__ Wq, const float* __restrict__ Wk,
    const float* __restrict__ Wv, const float* __restrict__ Wo,
    u16* __restrict__ Wqkv, u16* __restrict__ Wob) {
  const int i4 = (blockIdx.x * 256 + threadIdx.x) * 4;  // 0..262140
  fl4 a = *(const fl4*)(Wq + i4);
  fl4 b = *(const fl4*)(Wk + i4);
  fl4 c = *(const fl4*)(Wv + i4);
  fl4 d = *(const fl4*)(Wo + i4);
  us4 pa, pb, pc, pd;
#pragma unroll
  for (int t = 0; t < 4; ++t) {
    pa[t] = f2bf(a[t]); pb[t] = f2bf(b[t]);
    pc[t] = f2bf(c[t]); pd[t] = f2bf(d[t]);
  }
  *(us4*)(Wqkv + i4) = pa;
  *(us4*)(Wqkv + 262144 + i4) = pb;
  *(us4*)(Wqkv + 524288 + i4) = pc;
  *(us4*)(Wob + i4) = pd;
}

// ------------------------------------------------- fused QKV + attention
// grid: 2048 (one WG per (b,t)); 512 threads = 8 waves = 2 head-groups x 4.
// attn buffer doubles as x_bf16 scratch for the same (b,t): all x reads finish
// (final __syncthreads) before attn overwrites it from registers.
__global__ __launch_bounds__(512, 4) void qkv_attn_kernel(
    const float* __restrict__ x, const u16* __restrict__ Wqkv,
    const float* __restrict__ bq, const float* __restrict__ bk,
    const float* __restrict__ bv, u16* __restrict__ attn) {
  __shared__ u16 qs[2][64 * LQ];   // also holds P after softmax (wave-private rows)
  __shared__ u16 ks_[2][64 * LQ];
  __shared__ u16 vs[2][64 * LQ];   // stored transposed: vs[d][m]

  const int bt = blockIdx.x;
  const int tid = threadIdx.x;
  const int lane = tid & 63;
  const int wave = tid >> 6;
  const int grp = wave >> 2;  // head-group: 0 -> heads 0..3, 1 -> heads 4..7
  const int w = wave & 3;     // strip id within group
  const int l15 = lane & 15;
  const int l4 = lane >> 4;

  const float* xp = x + (size_t)bt * 32768;
  u16* xb = attn + (size_t)bt * 32768;  // bf16 x tile, parked in attn region

  // phase 0: convert x tile fp32 -> bf16 -> global (coalesced 16B stores)
#pragma unroll
  for (int i = 0; i < 8; ++i) {
    const int idx = i * 4096 + tid * 8;
    fl4 a = *(const fl4*)(xp + idx);
    fl4 b = *(const fl4*)(xp + idx + 4);
    us8 p;
    p[0] = f2bf(a[0]); p[1] = f2bf(a[1]); p[2] = f2bf(a[2]); p[3] = f2bf(a[3]);
    p[4] = f2bf(b[0]); p[5] = f2bf(b[1]); p[6] = f2bf(b[2]); p[7] = f2bf(b[3]);
    *(us8*)(xb + idx) = p;
  }
  __syncthreads();  // drains vmem: x_bf visible to all waves via L2

  const f4v fzero = {0.f, 0.f, 0.f, 0.f};
  unsigned opk[4][8];  // packed bf16 O, 4 heads x 16 values

#pragma unroll
  for (int hi = 0; hi < 4; ++hi) {
    const int h = grp * 4 + hi;
    // ---- QKV GEMM: wave computes cols [16w,16w+16) of q_h/k_h/v_h ----
    const int ncol = h * 64 + 16 * w + l15;
    const float bqv = bq[ncol];
    const float bkv = bk[ncol];
    const float bvv = bv[ncol];
    const u16* WqP = Wqkv + (size_t)ncol * 512 + l4 * 8;
    const u16* WkP = Wqkv + (size_t)(512 + ncol) * 512 + l4 * 8;
    const u16* WvP = Wqkv + (size_t)(1024 + ncol) * 512 + l4 * 8;

    f4v aq[4], ak[4], av[4];
#pragma unroll
    for (int i = 0; i < 4; ++i) { aq[i] = fzero; ak[i] = fzero; av[i] = fzero; }

#pragma unroll 4
    for (int kk = 0; kk < 16; ++kk) {
      const int ko = kk * 32 + l4 * 8;
      const s8v bq8 = ld16(WqP + kk * 32);  // weights: L2-resident
      const s8v bk8 = ld16(WkP + kk * 32);
      const s8v bv8 = ld16(WvP + kk * 32);
      const s8v a0 = ld16(xb + (0 + l15) * 512 + ko);   // x: L1/L2-resident
      const s8v a1 = ld16(xb + (16 + l15) * 512 + ko);
      const s8v a2 = ld16(xb + (32 + l15) * 512 + ko);
      const s8v a3 = ld16(xb + (48 + l15) * 512 + ko);
      aq[0] = mfma16(a0, bq8, aq[0]); aq[1] = mfma16(a1, bq8, aq[1]);
      aq[2] = mfma16(a2, bq8, aq[2]); aq[3] = mfma16(a3, bq8, aq[3]);
      ak[0] = mfma16(a0, bk8, ak[0]); ak[1] = mfma16(a1, bk8, ak[1]);
      ak[2] = mfma16(a2, bk8, ak[2]); ak[3] = mfma16(a3, bk8, ak[3]);
      av[0] = mfma16(a0, bv8, av[0]); av[1] = mfma16(a1, bv8, av[1]);
      av[2] = mfma16(a2, bv8, av[2]); av[3] = mfma16(a3, bv8, av[3]);
    }

    // epilogue: bias (+ 1/sqrt(DK) folded into q), write bf16 to LDS
    const int nl = 16 * w + l15;
#pragma unroll
    for (int i = 0; i < 4; ++i) {
#pragma unroll
      for (int r = 0; r < 4; ++r) {
        const int m = 16 * i + 4 * l4 + r;  // C-layout row
        qs[grp][m * LQ + nl] = f2bf((aq[i][r] + bqv) * 0.125f);
        ks_[grp][m * LQ + nl] = f2bf(ak[i][r] + bkv);
        vs[grp][nl * LQ + m] = f2bf(av[i][r] + bvv);  // transposed for PV B-frags
      }
    }
    __syncthreads();  // barrier 1: q/k/v tiles complete

    // ---- S = q' k^T : wave owns rows [16w,16w+16), all 64 cols ----
    f4v s[4];
#pragma unroll
    for (int j = 0; j < 4; ++j) s[j] = fzero;
#pragma unroll
    for (int kc = 0; kc < 2; ++kc) {
      const s8v af = ld16(&qs[grp][(16 * w + l15) * LQ + kc * 32 + l4 * 8]);
#pragma unroll
      for (int j = 0; j < 4; ++j) {
        const s8v bf = ld16(&ks_[grp][(16 * j + l15) * LQ + kc * 32 + l4 * 8]);
        s[j] = mfma16(af, bf, s[j]);
      }
    }
    // softmax over 64 cols: 4 regs (col-tiles) x 16 lanes of the quad-group
#pragma unroll
    for (int r = 0; r < 4; ++r) {
      float mx = fmaxf(fmaxf(s[0][r], s[1][r]), fmaxf(s[2][r], s[3][r]));
      mx = fmaxf(mx, __shfl_xor(mx, 1));
      mx = fmaxf(mx, __shfl_xor(mx, 2));
      mx = fmaxf(mx, __shfl_xor(mx, 4));
      mx = fmaxf(mx, __shfl_xor(mx, 8));
      float e0 = __expf(s[0][r] - mx);
      float e1 = __expf(s[1][r] - mx);
      float e2 = __expf(s[2][r] - mx);
      float e3 = __expf(s[3][r] - mx);
      float sm = e0 + e1 + e2 + e3;
      sm += __shfl_xor(sm, 1);
      sm += __shfl_xor(sm, 2);
      sm += __shfl_xor(sm, 4);
      sm += __shfl_xor(sm, 8);
      const float inv = __builtin_amdgcn_rcpf(sm);
      s[0][r] = e0 * inv; s[1][r] = e1 * inv;
      s[2][r] = e2 * inv; s[3][r] = e3 * inv;
    }
    // P: C-layout -> A-layout, overlaid on qs. Rows [16w,16w+16) are only ever
    // touched by this wave after barrier 1, so no extra barrier needed.
    u16* Ps = qs[grp];
#pragma unroll
    for (int j = 0; j < 4; ++j)
#pragma unroll
      for (int r = 0; r < 4; ++r)
        Ps[(16 * w + 4 * l4 + r) * LQ + 16 * j + l15] = f2bf(s[j][r]);

    // ---- O = P @ V : rows [16w,16w+16) ----
    f4v o[4];
#pragma unroll
    for (int j = 0; j < 4; ++j) o[j] = fzero;
#pragma unroll
    for (int kc = 0; kc < 2; ++kc) {
      const s8v af = ld16(&Ps[(16 * w + l15) * LQ + kc * 32 + l4 * 8]);
#pragma unroll
      for (int j = 0; j < 4; ++j) {
        const s8v bf = ld16(&vs[grp][(16 * j + l15) * LQ + kc * 32 + l4 * 8]);
        o[j] = mfma16(af, bf, o[j]);
      }
    }
    // pack O to bf16 registers (written to global after final barrier)
#pragma unroll
    for (int j = 0; j < 4; ++j) {
      opk[hi][j * 2 + 0] = (unsigned)f2bf(o[j][0]) | ((unsigned)f2bf(o[j][1]) << 16);
      opk[hi][j * 2 + 1] = (unsigned)f2bf(o[j][2]) | ((unsigned)f2bf(o[j][3]) << 16);
    }
    __syncthreads();  // barrier 2: LDS reuse next head-iter
  }

  // all x_bf reads are complete (last barrier) -> overwrite region with attn
#pragma unroll
  for (int hi = 0; hi < 4; ++hi) {
    const int h = grp * 4 + hi;
#pragma unroll
    for (int j = 0; j < 4; ++j) {
#pragma unroll
      for (int t = 0; t < 2; ++t) {
        const unsigned v = opk[hi][j * 2 + t];
        const int m = 16 * w + 4 * l4 + 2 * t;
        xb[(size_t)m * 512 + h * 64 + 16 * j + l15] = (u16)(v & 0xffffu);
        xb[(size_t)(m + 1) * 512 + h * 64 + 16 * j + l15] = (u16)(v >> 16);
      }
    }
  }
}

// ------------------------------------------------- output projection GEMM
// out[131072][512] = attn(bf16) @ Wo^T + bo ; 128x128 tiles, BK=32,
// m97 structure: global_load_lds width-16 staging, unpadded LDS, b128 frags.
__global__ __launch_bounds__(256) void out_proj_kernel(
    const u16* __restrict__ attn, const u16* __restrict__ Wob,
    const float* __restrict__ bo, float* __restrict__ out) {
  __shared__ u16 As[128 * 32];
  __shared__ u16 Bs[128 * 32];
  const int tid = threadIdx.x;
  const int lane = tid & 63;
  const int wv = tid >> 6;
  const int m0 = blockIdx.x * 128;
  const int n0 = blockIdx.y * 128;
  const int wy = wv >> 1;
  const int wx = wv & 1;
  const int l15 = lane & 15;
  const int l4 = lane >> 4;

  // staging map: wave wv stages rows [16wv,16wv+16) and [64+16wv, 64+16wv+16)
  const u16* gA = attn + (size_t)(m0 + 16 * wv + (lane >> 2)) * 512 + (lane & 3) * 8;
  const u16* gB = Wob + (size_t)(n0 + 16 * wv + (lane >> 2)) * 512 + (lane & 3) * 8;
  u16* lA = As + wv * 512;  // + lane*8 implicit (HW: base + lane*16B)
  u16* lB = Bs + wv * 512;

  const f4v fzero = {0.f, 0.f, 0.f, 0.f};
  f4v acc[4][4];
#pragma unroll
  for (int i = 0; i < 4; ++i)
#pragma unroll
    for (int j = 0; j < 4; ++j) acc[i][j] = fzero;

  for (int k0 = 0; k0 < 512; k0 += 32) {
    __syncthreads();
    ASYNC16(gA + k0, lA);
    ASYNC16(gA + 64 * 512 + k0, lA + 2048);
    ASYNC16(gB + k0, lB);
    ASYNC16(gB + 64 * 512 + k0, lB + 2048);
    __syncthreads();  // vmcnt(0) drain covers the LDS-DMA
    s8v a[4], b[4];
#pragma unroll
    for (int i = 0; i < 4; ++i)
      a[i] = ld16(&As[(wy * 64 + 16 * i + l15) * 32 + l4 * 8]);
#pragma unroll
    for (int j = 0; j < 4; ++j)
      b[j] = ld16(&Bs[(wx * 64 + 16 * j + l15) * 32 + l4 * 8]);
#pragma unroll
    for (int i = 0; i < 4; ++i)
#pragma unroll
      for (int j = 0; j < 4; ++j)
        acc[i][j] = mfma16(a[i], b[j], acc[i][j]);
  }
#pragma unroll
  for (int j = 0; j < 4; ++j) {
    const int col = n0 + wx * 64 + 16 * j + l15;
    const float bb = bo[col];
#pragma unroll
    for (int i = 0; i < 4; ++i) {
#pragma unroll
      for (int r = 0; r < 4; ++r) {
        const int row = m0 + wy * 64 + 16 * i + 4 * l4 + r;
        out[(size_t)row * 512 + col] = acc[i][j][r] + bb;
      }
    }
  }
}

extern "C" void kernel_launch(void* const* d_in, const int* in_sizes, int n_in,
                              void* d_out, int out_size, void* d_ws, size_t ws_size,
                              hipStream_t stream) {
  const float* x  = (const float*)d_in[0];
  const float* Wq = (const float*)d_in[1];
  const float* bq = (const float*)d_in[2];
  const float* Wk = (const float*)d_in[3];
  const float* bk = (const float*)d_in[4];
  const float* Wv = (const float*)d_in[5];
  const float* bv = (const float*)d_in[6];
  const float* Wo = (const float*)d_in[7];
  const float* bo = (const float*)d_in[8];
  float* out = (float*)d_out;

  // workspace layout (needs 136,314,880 B):
  u16* Wqkv = (u16*)d_ws;              // [1536][512] bf16 = 1,572,864 B
  u16* Wob  = Wqkv + 3 * 512 * 512;    // [512][512]  bf16 =   524,288 B
  u16* attn = Wob + 512 * 512;         // [131072][512] bf16 (doubles as x_bf16)

  pack_weights_kernel<<<256, 256, 0, stream>>>(Wq, Wk, Wv, Wo, Wqkv, Wob);
  qkv_attn_kernel<<<2048, 512, 0, stream>>>(x, Wqkv, bq, bk, bv, attn);
  out_proj_kernel<<<dim3(1024, 4), 256, 0, stream>>>(attn, Wob, bo, out);
}